// Round 11
// baseline (50.877 us; speedup 1.0000x reference)
//
#include <hip/hip_runtime.h>
#include <hip/hip_bf16.h>

// Fused causal self-attention: B=4096 independent (T=64, C=64) problems.
// R11 = R10 with block geometry 256 blocks x 512 threads (8 waves): ONE block
// per CU -> 16 resident waves/CU (was 8), weights staged once per CU. Each
// wave still pipelines two batches (b, b+2048) with x-prefetch; stores bounce
// through padded LDS for exact 64MB HBM writes (R10-verified). Weights in
// 32KB XOR-swizzled LDS. All matmuls v_mfma_f32_16x16x32_bf16; softmax via
// __shfl_xor; 1/8 folded into Wq.

typedef __attribute__((ext_vector_type(8))) short bf16x8;
typedef __attribute__((ext_vector_type(4))) short bf16x4;
typedef __attribute__((ext_vector_type(4))) float f32x4;

#define MFMA32(a, b, c) __builtin_amdgcn_mfma_f32_16x16x32_bf16(a, b, c, 0, 0, 0)
#define LOG2E 1.44269504088896f
#define BSTR 68   // bounce-buffer row stride in floats (64 + 4: breaks bank alias)

__device__ __forceinline__ unsigned short f2b(float f) {
    return __builtin_bit_cast(unsigned short, __float2bfloat16(f));   // RNE
}

__device__ __forceinline__ bf16x4 pack4(f32x4 a, float s) {
    bf16x4 r;
    r[0] = (short)f2b(a[0] * s); r[1] = (short)f2b(a[1] * s);
    r[2] = (short)f2b(a[2] * s); r[3] = (short)f2b(a[3] * s);
    return r;
}

__device__ __forceinline__ bf16x4 zero4() {
    bf16x4 r; r[0] = 0; r[1] = 0; r[2] = 0; r[3] = 0; return r;
}

__device__ __forceinline__ bf16x8 cat(bf16x4 lo, bf16x4 hi) {
    bf16x8 r;
    r[0] = lo[0]; r[1] = lo[1]; r[2] = lo[2]; r[3] = lo[3];
    r[4] = hi[0]; r[5] = hi[1]; r[6] = hi[2]; r[7] = hi[3];
    return r;
}

__device__ __forceinline__ bf16x8 cvt8(float4 a, float4 b) {
    bf16x8 r;
    r[0] = (short)f2b(a.x); r[1] = (short)f2b(a.y);
    r[2] = (short)f2b(a.z); r[3] = (short)f2b(a.w);
    r[4] = (short)f2b(b.x); r[5] = (short)f2b(b.y);
    r[6] = (short)f2b(b.z); r[7] = (short)f2b(b.w);
    return r;
}

// LDS weight addressing: [4][64][64] bf16, row = 128 B.
// XOR swizzle: elem col ^= (row&7)<<3 (byte ^= (row&7)<<4).
__device__ __forceinline__ int swz(int row, int col) {
    return row * 64 + (col ^ ((row & 7) << 3));
}

// ---- pre-kernel: convert weights fp32 -> bf16 into d_ws; Wq scaled by 1/8 ----
__global__ void cvt_w_kernel(const float* __restrict__ wk, const float* __restrict__ wq,
                             const float* __restrict__ wv, const float* __restrict__ wp,
                             unsigned short* __restrict__ dst) {
    int e = blockIdx.x * 256 + threadIdx.x;   // 0..16383
    int m = e >> 12;
    int off = e & 4095;
    const float* src = (m == 0) ? wk : (m == 1) ? wq : (m == 2) ? wv : wp;
    float s = (m == 1) ? 0.125f : 1.0f;       // 2^-3: exact in bf16
    dst[e] = f2b(src[off] * s);
}

// One full batch. xf in regs; output bounced through bnc (wave-private LDS).
__device__ __forceinline__ void compute_batch(
    const short* __restrict__ lw, float* __restrict__ bnc, const bf16x8 xf[8],
    const float* __restrict__ bp, float* __restrict__ ob, int lane, int r, int g)
{
    const short* Wk = lw;
    const short* Wq = lw + 4096;
    const short* Wv = lw + 8192;
    const short* Wp = lw + 12288;

    // kT = Wk @ xT
    bf16x8 kT8[2][4];
    #pragma unroll
    for (int cm2 = 0; cm2 < 2; ++cm2) {
        bf16x4 lo[4];
        #pragma unroll
        for (int h = 0; h < 2; ++h) {
            const int cm = cm2 * 2 + h;
            bf16x8 a0 = *(const bf16x8*)(Wk + swz(cm * 16 + r, g * 8));
            bf16x8 a1 = *(const bf16x8*)(Wk + swz(cm * 16 + r, 32 + g * 8));
            #pragma unroll
            for (int sm = 0; sm < 4; ++sm) {
                f32x4 acc = {0.f, 0.f, 0.f, 0.f};
                acc = MFMA32(a0, xf[sm * 2], acc);
                acc = MFMA32(a1, xf[sm * 2 + 1], acc);
                if (h == 0) lo[sm] = pack4(acc, 1.0f);
                else kT8[cm2][sm] = cat(lo[sm], pack4(acc, 1.0f));
            }
        }
    }

    // qT = (Wq/8) @ xT
    bf16x8 q8[2][4];
    #pragma unroll
    for (int cm2 = 0; cm2 < 2; ++cm2) {
        bf16x4 lo[4];
        #pragma unroll
        for (int h = 0; h < 2; ++h) {
            const int cm = cm2 * 2 + h;
            bf16x8 a0 = *(const bf16x8*)(Wq + swz(cm * 16 + r, g * 8));
            bf16x8 a1 = *(const bf16x8*)(Wq + swz(cm * 16 + r, 32 + g * 8));
            #pragma unroll
            for (int tt = 0; tt < 4; ++tt) {
                f32x4 acc = {0.f, 0.f, 0.f, 0.f};
                acc = MFMA32(a0, xf[tt * 2], acc);
                acc = MFMA32(a1, xf[tt * 2 + 1], acc);
                if (h == 0) lo[tt] = pack4(acc, 1.0f);
                else q8[cm2][tt] = cat(lo[tt], pack4(acc, 1.0f));
            }
        }
    }

    // scores + softmax -> P  (lane: col t = tn*16+r, rows s = sm*16+g*4+j)
    bf16x4 P[4][4];
    #pragma unroll
    for (int tn = 0; tn < 4; ++tn) {
        f32x4 st[4];
        #pragma unroll
        for (int sm = 0; sm < 4; ++sm) {
            if (sm > tn) continue;
            f32x4 acc = {0.f, 0.f, 0.f, 0.f};
            acc = MFMA32(kT8[0][sm], q8[0][tn], acc);
            acc = MFMA32(kT8[1][sm], q8[1][tn], acc);
            st[sm] = acc;
        }
        float mx = -1e30f;
        #pragma unroll
        for (int sm = 0; sm < 4; ++sm) {
            if (sm > tn) continue;
            #pragma unroll
            for (int j = 0; j < 4; ++j) {
                float v = st[sm][j];
                if (sm == tn) v = ((g * 4 + j) <= r) ? v : -1e30f;  // causal
                st[sm][j] = v;
                mx = fmaxf(mx, v);
            }
        }
        mx = fmaxf(mx, __shfl_xor(mx, 16));
        mx = fmaxf(mx, __shfl_xor(mx, 32));
        float sum = 0.f;
        #pragma unroll
        for (int sm = 0; sm < 4; ++sm) {
            if (sm > tn) continue;
            #pragma unroll
            for (int j = 0; j < 4; ++j) {
                float e = exp2f((st[sm][j] - mx) * LOG2E);
                st[sm][j] = e;
                sum += e;
            }
        }
        sum += __shfl_xor(sum, 16);
        sum += __shfl_xor(sum, 32);
        float inv = __builtin_amdgcn_rcpf(sum);   // sum >= 1 (diagonal present)
        #pragma unroll
        for (int sm = 0; sm < 4; ++sm)
            P[sm][tn] = (sm <= tn) ? pack4(st[sm], inv) : zero4();
    }

    // v = x @ WvT
    bf16x8 v8[4][2];
    #pragma unroll
    for (int cm = 0; cm < 4; ++cm) {
        bf16x8 b0 = *(const bf16x8*)(Wv + swz(cm * 16 + r, g * 8));
        bf16x8 b1 = *(const bf16x8*)(Wv + swz(cm * 16 + r, 32 + g * 8));
        bf16x4 tmp[4];
        #pragma unroll
        for (int tv = 0; tv < 4; ++tv) {
            f32x4 acc = {0.f, 0.f, 0.f, 0.f};
            acc = MFMA32(xf[tv * 2], b0, acc);
            acc = MFMA32(xf[tv * 2 + 1], b1, acc);
            tmp[tv] = pack4(acc, 1.0f);
        }
        v8[cm][0] = cat(tmp[0], tmp[1]);
        v8[cm][1] = cat(tmp[2], tmp[3]);
    }

    // out2T = v * PT
    bf16x8 o28[4][2];
    #pragma unroll
    for (int tn = 0; tn < 4; ++tn) {
        bf16x8 pt80 = cat(P[0][tn], P[1][tn]);
        bf16x8 pt81 = cat(P[2][tn], P[3][tn]);
        bf16x4 c[4];
        #pragma unroll
        for (int cm = 0; cm < 4; ++cm) {
            f32x4 acc = {0.f, 0.f, 0.f, 0.f};
            acc = MFMA32(v8[cm][0], pt80, acc);
            if (tn >= 2) acc = MFMA32(v8[cm][1], pt81, acc);
            c[cm] = pack4(acc, 1.0f);
        }
        o28[tn][0] = cat(c[0], c[1]);
        o28[tn][1] = cat(c[2], c[3]);
    }

    // resT = Wp @ out2T + bias; bounce through LDS; coalesced 1KB stores.
    bf16x8 wp0[4], wp1[4];
    float4 bias4[4];
    #pragma unroll
    for (int om = 0; om < 4; ++om) {
        wp0[om] = cat(*(const bf16x4*)(Wp + swz(om * 16 + r, g * 4)),
                      *(const bf16x4*)(Wp + swz(om * 16 + r, 16 + g * 4)));
        wp1[om] = cat(*(const bf16x4*)(Wp + swz(om * 16 + r, 32 + g * 4)),
                      *(const bf16x4*)(Wp + swz(om * 16 + r, 48 + g * 4)));
        bias4[om] = *(const float4*)(bp + om * 16 + g * 4);
    }
    #pragma unroll
    for (int tn = 0; tn < 4; ++tn) {
        // frag: row t = tn*16+r, cols om*16+g*4+j -> LDS[r][om*16+g*4]
        #pragma unroll
        for (int om = 0; om < 4; ++om) {
            f32x4 acc = {0.f, 0.f, 0.f, 0.f};
            acc = MFMA32(wp0[om], o28[tn][0], acc);
            acc = MFMA32(wp1[om], o28[tn][1], acc);
            float4 o;
            o.x = acc[0] + bias4[om].x; o.y = acc[1] + bias4[om].y;
            o.z = acc[2] + bias4[om].z; o.w = acc[3] + bias4[om].w;
            *(float4*)(bnc + r * BSTR + om * 16 + g * 4) = o;
        }
        asm volatile("s_waitcnt lgkmcnt(0)" ::: "memory");  // writes visible wave-wide
        // read back linearly, store 4 x 1KB contiguous (full 128B lines)
        #pragma unroll
        for (int i = 0; i < 4; ++i) {
            float4 v = *(const float4*)(bnc + (i * 4 + (lane >> 4)) * BSTR + (lane & 15) * 4);
            *(float4*)(ob + tn * 1024 + i * 256 + lane * 4) = v;
        }
        asm volatile("" ::: "memory");  // keep next tn's LDS writes after these reads
    }
}

__global__ __launch_bounds__(512, 4) void attn_fused_kernel(
    const float* __restrict__ x,              // [4096,64,64] fp32
    const unsigned short* __restrict__ wbf,   // bf16: Wk, Wq(/8), Wv, Wp
    const float* __restrict__ bp,             // [64] fp32
    float* __restrict__ out)                  // [4096,64,64] fp32
{
    __shared__ short lw[16384];               // 32 KB weights, swizzled
    __shared__ float lbounce[8 * 16 * BSTR];  // 8 waves x 16-row bounce (34 KB)

    const int tid  = threadIdx.x;             // 0..511
    const int wv_  = tid >> 6;                // 0..7
    const int lane = tid & 63;
    const int r = lane & 15;
    const int g = lane >> 4;
    float* bnc = lbounce + wv_ * (16 * BSTR);
    const long b0 = (long)blockIdx.x * 8 + wv_;     // [0, 2048)
    const long b1 = b0 + 2048;

    // ---- issue batch-0 x loads ----
    const float* xb0 = x + b0 * 4096;
    float4 raw[8][2];
    #pragma unroll
    for (int f = 0; f < 8; ++f) {
        const float* p = xb0 + ((f >> 1) * 16 + r) * 64 + (f & 1) * 32 + g * 8;
        raw[f][0] = *(const float4*)p;
        raw[f][1] = *(const float4*)(p + 4);
    }

    // ---- stage weights to LDS (swizzled); 512 threads x 64 B each ----
    {
        const int row  = tid >> 1;            // 0..255 ([4][64] rows)
        const int half = tid & 1;             // which 32-elem half of the row
        #pragma unroll
        for (int i = 0; i < 4; ++i) {
            const int grp = half * 4 + i;     // 8-elem group index 0..7
            bf16x8 v = *(const bf16x8*)(wbf + row * 64 + grp * 8);
            *(bf16x8*)(lw + row * 64 + ((grp ^ (row & 7)) * 8)) = v;
        }
    }

    // ---- convert batch-0 x to bf16 frags ----
    bf16x8 xf[8];
    #pragma unroll
    for (int f = 0; f < 8; ++f)
        xf[f] = cvt8(raw[f][0], raw[f][1]);

    __syncthreads();                          // weights visible (drains vmem too)

    // ---- PREFETCH batch-1 x: flies under batch-0's whole compute ----
    const float* xb1 = x + b1 * 4096;
    float4 raw1[8][2];
    #pragma unroll
    for (int f = 0; f < 8; ++f) {
        const float* p = xb1 + ((f >> 1) * 16 + r) * 64 + (f & 1) * 32 + g * 8;
        raw1[f][0] = *(const float4*)p;
        raw1[f][1] = *(const float4*)(p + 4);
    }

    // ---- batch 0: compute + store (stores drain under batch 1) ----
    compute_batch(lw, bnc, xf, bp, out + b0 * 4096, lane, r, g);

    // ---- batch 1: convert (waits prefetch), compute + store ----
    bf16x8 xf1[8];
    #pragma unroll
    for (int f = 0; f < 8; ++f)
        xf1[f] = cvt8(raw1[f][0], raw1[f][1]);

    compute_batch(lw, bnc, xf1, bp, out + b1 * 4096, lane, r, g);
}

extern "C" void kernel_launch(void* const* d_in, const int* in_sizes, int n_in,
                              void* d_out, int out_size, void* d_ws, size_t ws_size,
                              hipStream_t stream) {
    const float* x  = (const float*)d_in[0];
    const float* wk = (const float*)d_in[1];
    const float* wq = (const float*)d_in[2];
    const float* wv = (const float*)d_in[3];
    const float* wp = (const float*)d_in[4];
    const float* bp = (const float*)d_in[5];
    unsigned short* wbf = (unsigned short*)d_ws;   // 16384 bf16 = 32 KB

    cvt_w_kernel<<<64, 256, 0, stream>>>(wk, wq, wv, wp, wbf);
    attn_fused_kernel<<<256, 512, 0, stream>>>(x, wbf, bp, (float*)d_out);
}

// Round 12
// 37.008 us; speedup vs baseline: 1.3748x; 1.3748x over previous
//
#include <hip/hip_runtime.h>
#include <hip/hip_bf16.h>

// Fused causal self-attention: B=4096 independent (T=64, C=64) problems.
// R12: full-grid residency with R10's proven 256-thread codegen.
// 1024 blocks x 256 thr (4 waves), ONE batch per wave, 4 blocks/CU exactly
// (grid == resident capacity -> no tail). LDS = 32KB swizzled weights +
// 8KB bounce (16x32 floats/wave, XOR-swizzled) = 40960 B -> 4 blocks/CU.
// Projection stores bounce through LDS in two om-pair halves and emit
// 128B-contiguous aligned segments (kills the 1.55x write amplification;
// R10-verified). All matmuls v_mfma_f32_16x16x32_bf16; softmax __shfl_xor;
// 1/8 folded into Wq. R11 lesson: 512-thr geometry spilled ~50 regs -> avoid.

typedef __attribute__((ext_vector_type(8))) short bf16x8;
typedef __attribute__((ext_vector_type(4))) short bf16x4;
typedef __attribute__((ext_vector_type(4))) float f32x4;

#define MFMA32(a, b, c) __builtin_amdgcn_mfma_f32_16x16x32_bf16(a, b, c, 0, 0, 0)
#define LOG2E 1.44269504088896f

__device__ __forceinline__ unsigned short f2b(float f) {
    return __builtin_bit_cast(unsigned short, __float2bfloat16(f));   // RNE
}

__device__ __forceinline__ bf16x4 pack4(f32x4 a, float s) {
    bf16x4 r;
    r[0] = (short)f2b(a[0] * s); r[1] = (short)f2b(a[1] * s);
    r[2] = (short)f2b(a[2] * s); r[3] = (short)f2b(a[3] * s);
    return r;
}

__device__ __forceinline__ bf16x4 zero4() {
    bf16x4 r; r[0] = 0; r[1] = 0; r[2] = 0; r[3] = 0; return r;
}

__device__ __forceinline__ bf16x8 cat(bf16x4 lo, bf16x4 hi) {
    bf16x8 r;
    r[0] = lo[0]; r[1] = lo[1]; r[2] = lo[2]; r[3] = lo[3];
    r[4] = hi[0]; r[5] = hi[1]; r[6] = hi[2]; r[7] = hi[3];
    return r;
}

__device__ __forceinline__ bf16x8 cvt8(float4 a, float4 b) {
    bf16x8 r;
    r[0] = (short)f2b(a.x); r[1] = (short)f2b(a.y);
    r[2] = (short)f2b(a.z); r[3] = (short)f2b(a.w);
    r[4] = (short)f2b(b.x); r[5] = (short)f2b(b.y);
    r[6] = (short)f2b(b.z); r[7] = (short)f2b(b.w);
    return r;
}

// LDS weight addressing: [4][64][64] bf16, row = 128 B.
// XOR swizzle: elem col ^= (row&7)<<3 (byte ^= (row&7)<<4).
__device__ __forceinline__ int swz(int row, int col) {
    return row * 64 + (col ^ ((row & 7) << 3));
}

// ---- pre-kernel: convert weights fp32 -> bf16 into d_ws; Wq scaled by 1/8 ----
__global__ void cvt_w_kernel(const float* __restrict__ wk, const float* __restrict__ wq,
                             const float* __restrict__ wv, const float* __restrict__ wp,
                             unsigned short* __restrict__ dst) {
    int e = blockIdx.x * 256 + threadIdx.x;   // 0..16383
    int m = e >> 12;
    int off = e & 4095;
    const float* src = (m == 0) ? wk : (m == 1) ? wq : (m == 2) ? wv : wp;
    float s = (m == 1) ? 0.125f : 1.0f;       // 2^-3: exact in bf16
    dst[e] = f2b(src[off] * s);
}

__global__ __launch_bounds__(256, 4) void attn_fused_kernel(
    const float* __restrict__ x,              // [4096,64,64] fp32
    const unsigned short* __restrict__ wbf,   // bf16: Wk, Wq(/8), Wv, Wp
    const float* __restrict__ bp,             // [64] fp32
    float* __restrict__ out)                  // [4096,64,64] fp32
{
    __shared__ short lw[16384];               // 32 KB weights, swizzled
    __shared__ float lbounce[4 * 16 * 32];    // 4 waves x 16x32 bounce (8 KB)

    const int tid  = threadIdx.x;
    const int wv_  = tid >> 6;
    const int lane = tid & 63;
    const int r = lane & 15;
    const int g = lane >> 4;
    float* bnc = lbounce + wv_ * (16 * 32);
    const long b = (long)blockIdx.x * 4 + wv_;      // [0, 4096)

    // ---- issue x loads (16 x float4, coalesced) ----
    const float* xb = x + b * 4096;
    float4 raw[8][2];
    #pragma unroll
    for (int f = 0; f < 8; ++f) {
        const float* p = xb + ((f >> 1) * 16 + r) * 64 + (f & 1) * 32 + g * 8;
        raw[f][0] = *(const float4*)p;
        raw[f][1] = *(const float4*)(p + 4);
    }

    // ---- stage weights to LDS (swizzled), 128 B per thread ----
    {
        const int rw = tid;                   // 0..255 ([4][64] rows)
        #pragma unroll
        for (int i = 0; i < 8; ++i) {
            bf16x8 v = *(const bf16x8*)(wbf + rw * 64 + i * 8);
            *(bf16x8*)(lw + rw * 64 + ((i ^ (rw & 7)) * 8)) = v;
        }
    }

    // ---- convert x to bf16 frags ----
    bf16x8 xf[8];                             // frag f: t=(f>>1)*16+r, c=(f&1)*32+g*8..
    #pragma unroll
    for (int f = 0; f < 8; ++f)
        xf[f] = cvt8(raw[f][0], raw[f][1]);

    __syncthreads();                          // weights visible to all waves

    const short* Wk = lw;
    const short* Wq = lw + 4096;
    const short* Wv = lw + 8192;
    const short* Wp = lw + 12288;

    // ---- kT = Wk @ xT -> kT8[cm2][sm] ----
    bf16x8 kT8[2][4];
    #pragma unroll
    for (int cm2 = 0; cm2 < 2; ++cm2) {
        bf16x4 lo[4];
        #pragma unroll
        for (int h = 0; h < 2; ++h) {
            const int cm = cm2 * 2 + h;
            bf16x8 a0 = *(const bf16x8*)(Wk + swz(cm * 16 + r, g * 8));
            bf16x8 a1 = *(const bf16x8*)(Wk + swz(cm * 16 + r, 32 + g * 8));
            #pragma unroll
            for (int sm = 0; sm < 4; ++sm) {
                f32x4 acc = {0.f, 0.f, 0.f, 0.f};
                acc = MFMA32(a0, xf[sm * 2], acc);
                acc = MFMA32(a1, xf[sm * 2 + 1], acc);
                if (h == 0) lo[sm] = pack4(acc, 1.0f);
                else kT8[cm2][sm] = cat(lo[sm], pack4(acc, 1.0f));
            }
        }
    }

    // ---- qT = (Wq/8) @ xT -> q8[cm2][tt] ----
    bf16x8 q8[2][4];
    #pragma unroll
    for (int cm2 = 0; cm2 < 2; ++cm2) {
        bf16x4 lo[4];
        #pragma unroll
        for (int h = 0; h < 2; ++h) {
            const int cm = cm2 * 2 + h;
            bf16x8 a0 = *(const bf16x8*)(Wq + swz(cm * 16 + r, g * 8));
            bf16x8 a1 = *(const bf16x8*)(Wq + swz(cm * 16 + r, 32 + g * 8));
            #pragma unroll
            for (int tt = 0; tt < 4; ++tt) {
                f32x4 acc = {0.f, 0.f, 0.f, 0.f};
                acc = MFMA32(a0, xf[tt * 2], acc);
                acc = MFMA32(a1, xf[tt * 2 + 1], acc);
                if (h == 0) lo[tt] = pack4(acc, 1.0f);
                else q8[cm2][tt] = cat(lo[tt], pack4(acc, 1.0f));
            }
        }
    }

    // ---- scores + softmax -> P  (lane: col t = tn*16+r, rows s = sm*16+g*4+j) ----
    bf16x4 P[4][4];
    #pragma unroll
    for (int tn = 0; tn < 4; ++tn) {
        f32x4 st[4];
        #pragma unroll
        for (int sm = 0; sm < 4; ++sm) {
            if (sm > tn) continue;
            f32x4 acc = {0.f, 0.f, 0.f, 0.f};
            acc = MFMA32(kT8[0][sm], q8[0][tn], acc);
            acc = MFMA32(kT8[1][sm], q8[1][tn], acc);
            st[sm] = acc;
        }
        float mx = -1e30f;
        #pragma unroll
        for (int sm = 0; sm < 4; ++sm) {
            if (sm > tn) continue;
            #pragma unroll
            for (int j = 0; j < 4; ++j) {
                float v = st[sm][j];
                if (sm == tn) v = ((g * 4 + j) <= r) ? v : -1e30f;  // causal
                st[sm][j] = v;
                mx = fmaxf(mx, v);
            }
        }
        mx = fmaxf(mx, __shfl_xor(mx, 16));
        mx = fmaxf(mx, __shfl_xor(mx, 32));
        float sum = 0.f;
        #pragma unroll
        for (int sm = 0; sm < 4; ++sm) {
            if (sm > tn) continue;
            #pragma unroll
            for (int j = 0; j < 4; ++j) {
                float e = exp2f((st[sm][j] - mx) * LOG2E);
                st[sm][j] = e;
                sum += e;
            }
        }
        sum += __shfl_xor(sum, 16);
        sum += __shfl_xor(sum, 32);
        float inv = __builtin_amdgcn_rcpf(sum);   // sum >= 1 (diagonal present)
        #pragma unroll
        for (int sm = 0; sm < 4; ++sm)
            P[sm][tn] = (sm <= tn) ? pack4(st[sm], inv) : zero4();
    }
    // kT8, q8 dead.

    // ---- v = x @ WvT -> v8[cm][sm2] ----
    bf16x8 v8[4][2];
    #pragma unroll
    for (int cm = 0; cm < 4; ++cm) {
        bf16x8 b0 = *(const bf16x8*)(Wv + swz(cm * 16 + r, g * 8));
        bf16x8 b1 = *(const bf16x8*)(Wv + swz(cm * 16 + r, 32 + g * 8));
        bf16x4 tmp[4];
        #pragma unroll
        for (int tv = 0; tv < 4; ++tv) {
            f32x4 acc = {0.f, 0.f, 0.f, 0.f};
            acc = MFMA32(xf[tv * 2], b0, acc);
            acc = MFMA32(xf[tv * 2 + 1], b1, acc);
            tmp[tv] = pack4(acc, 1.0f);
        }
        v8[cm][0] = cat(tmp[0], tmp[1]);
        v8[cm][1] = cat(tmp[2], tmp[3]);
    }
    // xf dead.

    // ---- out2T = v * PT -> o28[tn][cm2] ----
    bf16x8 o28[4][2];
    #pragma unroll
    for (int tn = 0; tn < 4; ++tn) {
        bf16x8 pt80 = cat(P[0][tn], P[1][tn]);
        bf16x8 pt81 = cat(P[2][tn], P[3][tn]);
        bf16x4 c[4];
        #pragma unroll
        for (int cm = 0; cm < 4; ++cm) {
            f32x4 acc = {0.f, 0.f, 0.f, 0.f};
            acc = MFMA32(v8[cm][0], pt80, acc);
            if (tn >= 2) acc = MFMA32(v8[cm][1], pt81, acc);
            c[cm] = pack4(acc, 1.0f);
        }
        o28[tn][0] = cat(c[0], c[1]);
        o28[tn][1] = cat(c[2], c[3]);
    }
    // P, v8 dead.

    // ---- resT = Wp @ out2T + bias; bounce 16x32 (XOR-swizzled); 128B stores ----
    bf16x8 wp0[4], wp1[4];
    float4 bias4[4];
    #pragma unroll
    for (int om = 0; om < 4; ++om) {
        wp0[om] = cat(*(const bf16x4*)(Wp + swz(om * 16 + r, g * 4)),
                      *(const bf16x4*)(Wp + swz(om * 16 + r, 16 + g * 4)));
        wp1[om] = cat(*(const bf16x4*)(Wp + swz(om * 16 + r, 32 + g * 4)),
                      *(const bf16x4*)(Wp + swz(om * 16 + r, 48 + g * 4)));
        bias4[om] = *(const float4*)(bp + om * 16 + g * 4);
    }
    float* ob = out + b * 4096;
    #pragma unroll
    for (int tn = 0; tn < 4; ++tn) {
        #pragma unroll
        for (int h = 0; h < 2; ++h) {         // om-pair half: output cols h*32..h*32+31
            #pragma unroll
            for (int oh = 0; oh < 2; ++oh) {
                const int om = h * 2 + oh;
                f32x4 acc = {0.f, 0.f, 0.f, 0.f};
                acc = MFMA32(wp0[om], o28[tn][0], acc);
                acc = MFMA32(wp1[om], o28[tn][1], acc);
                float4 o;
                o.x = acc[0] + bias4[om].x; o.y = acc[1] + bias4[om].y;
                o.z = acc[2] + bias4[om].z; o.w = acc[3] + bias4[om].w;
                // lane (r,g): res[t=tn*16+r][o=om*16+g*4..+3] -> bounce[r][c^swz]
                const int c = oh * 16 + g * 4;
                *(float4*)(bnc + r * 32 + (c ^ ((r & 7) << 2))) = o;
            }
            asm volatile("s_waitcnt lgkmcnt(0)" ::: "memory");
            // readback: 2 instrs x 8 rows x 128B contiguous aligned segments
            #pragma unroll
            for (int i = 0; i < 2; ++i) {
                const int row = i * 8 + (lane >> 3);
                const int cb  = (lane & 7) * 4;
                float4 v = *(const float4*)(bnc + row * 32 + (cb ^ ((row & 7) << 2)));
                *(float4*)(ob + (tn * 16 + row) * 64 + h * 32 + cb) = v;
            }
            asm volatile("" ::: "memory");    // keep next half's writes after reads
        }
    }
}

extern "C" void kernel_launch(void* const* d_in, const int* in_sizes, int n_in,
                              void* d_out, int out_size, void* d_ws, size_t ws_size,
                              hipStream_t stream) {
    const float* x  = (const float*)d_in[0];
    const float* wk = (const float*)d_in[1];
    const float* wq = (const float*)d_in[2];
    const float* wv = (const float*)d_in[3];
    const float* wp = (const float*)d_in[4];
    const float* bp = (const float*)d_in[5];
    unsigned short* wbf = (unsigned short*)d_ws;   // 16384 bf16 = 32 KB

    cvt_w_kernel<<<64, 256, 0, stream>>>(wk, wq, wv, wp, wbf);
    attn_fused_kernel<<<1024, 256, 0, stream>>>(x, wbf, bp, (float*)d_out);
}

// Round 13
// 29.524 us; speedup vs baseline: 1.7232x; 1.2535x over previous
//
#include <hip/hip_runtime.h>
#include <hip/hip_bf16.h>

// Fused causal self-attention: B=4096 independent (T=64, C=64) problems.
// R13 = R10 (best: 32.8us) with the weight-conversion pre-kernel FUSED into
// the attention kernel: each block stages all 4 weight matrices straight from
// the fp32 inputs into XOR-swizzled LDS (wave w converts matrix w; 1/8 scale
// folded into Wq, exact 2^-3). One kernel launch total.
// Structure (R10-proven): 512 blocks x 4 waves; each wave pipelines batches
// (b, b+2048) with x-prefetch; projection bounces through padded LDS for
// exact-64MB coalesced HBM writes; all matmuls v_mfma_f32_16x16x32_bf16;
// softmax via __shfl_xor lane bits 4,5.

typedef __attribute__((ext_vector_type(8))) short bf16x8;
typedef __attribute__((ext_vector_type(4))) short bf16x4;
typedef __attribute__((ext_vector_type(4))) float f32x4;

#define MFMA32(a, b, c) __builtin_amdgcn_mfma_f32_16x16x32_bf16(a, b, c, 0, 0, 0)
#define LOG2E 1.44269504088896f
#define BSTR 68   // bounce-buffer row stride in floats (64 + 4: breaks bank alias)

__device__ __forceinline__ unsigned short f2b(float f) {
    return __builtin_bit_cast(unsigned short, __float2bfloat16(f));   // RNE
}

__device__ __forceinline__ bf16x4 pack4(f32x4 a, float s) {
    bf16x4 r;
    r[0] = (short)f2b(a[0] * s); r[1] = (short)f2b(a[1] * s);
    r[2] = (short)f2b(a[2] * s); r[3] = (short)f2b(a[3] * s);
    return r;
}

__device__ __forceinline__ bf16x4 zero4() {
    bf16x4 r; r[0] = 0; r[1] = 0; r[2] = 0; r[3] = 0; return r;
}

__device__ __forceinline__ bf16x8 cat(bf16x4 lo, bf16x4 hi) {
    bf16x8 r;
    r[0] = lo[0]; r[1] = lo[1]; r[2] = lo[2]; r[3] = lo[3];
    r[4] = hi[0]; r[5] = hi[1]; r[6] = hi[2]; r[7] = hi[3];
    return r;
}

__device__ __forceinline__ bf16x8 cvt8(float4 a, float4 b) {
    bf16x8 r;
    r[0] = (short)f2b(a.x); r[1] = (short)f2b(a.y);
    r[2] = (short)f2b(a.z); r[3] = (short)f2b(a.w);
    r[4] = (short)f2b(b.x); r[5] = (short)f2b(b.y);
    r[6] = (short)f2b(b.z); r[7] = (short)f2b(b.w);
    return r;
}

__device__ __forceinline__ bf16x8 cvt8s(float4 a, float4 b, float s) {
    bf16x8 r;
    r[0] = (short)f2b(a.x * s); r[1] = (short)f2b(a.y * s);
    r[2] = (short)f2b(a.z * s); r[3] = (short)f2b(a.w * s);
    r[4] = (short)f2b(b.x * s); r[5] = (short)f2b(b.y * s);
    r[6] = (short)f2b(b.z * s); r[7] = (short)f2b(b.w * s);
    return r;
}

// LDS weight addressing: [4][64][64] bf16, row = 128 B.
// XOR swizzle: elem col ^= (row&7)<<3 (byte ^= (row&7)<<4).
__device__ __forceinline__ int swz(int row, int col) {
    return row * 64 + (col ^ ((row & 7) << 3));
}

// One full batch. xf in regs; output bounced through bnc (wave-private LDS).
__device__ __forceinline__ void compute_batch(
    const short* __restrict__ lw, float* __restrict__ bnc, const bf16x8 xf[8],
    const float* __restrict__ bp, float* __restrict__ ob, int lane, int r, int g)
{
    const short* Wk = lw;
    const short* Wq = lw + 4096;
    const short* Wv = lw + 8192;
    const short* Wp = lw + 12288;

    // kT = Wk @ xT
    bf16x8 kT8[2][4];
    #pragma unroll
    for (int cm2 = 0; cm2 < 2; ++cm2) {
        bf16x4 lo[4];
        #pragma unroll
        for (int h = 0; h < 2; ++h) {
            const int cm = cm2 * 2 + h;
            bf16x8 a0 = *(const bf16x8*)(Wk + swz(cm * 16 + r, g * 8));
            bf16x8 a1 = *(const bf16x8*)(Wk + swz(cm * 16 + r, 32 + g * 8));
            #pragma unroll
            for (int sm = 0; sm < 4; ++sm) {
                f32x4 acc = {0.f, 0.f, 0.f, 0.f};
                acc = MFMA32(a0, xf[sm * 2], acc);
                acc = MFMA32(a1, xf[sm * 2 + 1], acc);
                if (h == 0) lo[sm] = pack4(acc, 1.0f);
                else kT8[cm2][sm] = cat(lo[sm], pack4(acc, 1.0f));
            }
        }
    }

    // qT = (Wq/8) @ xT
    bf16x8 q8[2][4];
    #pragma unroll
    for (int cm2 = 0; cm2 < 2; ++cm2) {
        bf16x4 lo[4];
        #pragma unroll
        for (int h = 0; h < 2; ++h) {
            const int cm = cm2 * 2 + h;
            bf16x8 a0 = *(const bf16x8*)(Wq + swz(cm * 16 + r, g * 8));
            bf16x8 a1 = *(const bf16x8*)(Wq + swz(cm * 16 + r, 32 + g * 8));
            #pragma unroll
            for (int tt = 0; tt < 4; ++tt) {
                f32x4 acc = {0.f, 0.f, 0.f, 0.f};
                acc = MFMA32(a0, xf[tt * 2], acc);
                acc = MFMA32(a1, xf[tt * 2 + 1], acc);
                if (h == 0) lo[tt] = pack4(acc, 1.0f);
                else q8[cm2][tt] = cat(lo[tt], pack4(acc, 1.0f));
            }
        }
    }

    // scores + softmax -> P  (lane: col t = tn*16+r, rows s = sm*16+g*4+j)
    bf16x4 P[4][4];
    #pragma unroll
    for (int tn = 0; tn < 4; ++tn) {
        f32x4 st[4];
        #pragma unroll
        for (int sm = 0; sm < 4; ++sm) {
            if (sm > tn) continue;
            f32x4 acc = {0.f, 0.f, 0.f, 0.f};
            acc = MFMA32(kT8[0][sm], q8[0][tn], acc);
            acc = MFMA32(kT8[1][sm], q8[1][tn], acc);
            st[sm] = acc;
        }
        float mx = -1e30f;
        #pragma unroll
        for (int sm = 0; sm < 4; ++sm) {
            if (sm > tn) continue;
            #pragma unroll
            for (int j = 0; j < 4; ++j) {
                float v = st[sm][j];
                if (sm == tn) v = ((g * 4 + j) <= r) ? v : -1e30f;  // causal
                st[sm][j] = v;
                mx = fmaxf(mx, v);
            }
        }
        mx = fmaxf(mx, __shfl_xor(mx, 16));
        mx = fmaxf(mx, __shfl_xor(mx, 32));
        float sum = 0.f;
        #pragma unroll
        for (int sm = 0; sm < 4; ++sm) {
            if (sm > tn) continue;
            #pragma unroll
            for (int j = 0; j < 4; ++j) {
                float e = exp2f((st[sm][j] - mx) * LOG2E);
                st[sm][j] = e;
                sum += e;
            }
        }
        sum += __shfl_xor(sum, 16);
        sum += __shfl_xor(sum, 32);
        float inv = __builtin_amdgcn_rcpf(sum);   // sum >= 1 (diagonal present)
        #pragma unroll
        for (int sm = 0; sm < 4; ++sm)
            P[sm][tn] = (sm <= tn) ? pack4(st[sm], inv) : zero4();
    }

    // v = x @ WvT
    bf16x8 v8[4][2];
    #pragma unroll
    for (int cm = 0; cm < 4; ++cm) {
        bf16x8 b0 = *(const bf16x8*)(Wv + swz(cm * 16 + r, g * 8));
        bf16x8 b1 = *(const bf16x8*)(Wv + swz(cm * 16 + r, 32 + g * 8));
        bf16x4 tmp[4];
        #pragma unroll
        for (int tv = 0; tv < 4; ++tv) {
            f32x4 acc = {0.f, 0.f, 0.f, 0.f};
            acc = MFMA32(xf[tv * 2], b0, acc);
            acc = MFMA32(xf[tv * 2 + 1], b1, acc);
            tmp[tv] = pack4(acc, 1.0f);
        }
        v8[cm][0] = cat(tmp[0], tmp[1]);
        v8[cm][1] = cat(tmp[2], tmp[3]);
    }

    // out2T = v * PT
    bf16x8 o28[4][2];
    #pragma unroll
    for (int tn = 0; tn < 4; ++tn) {
        bf16x8 pt80 = cat(P[0][tn], P[1][tn]);
        bf16x8 pt81 = cat(P[2][tn], P[3][tn]);
        bf16x4 c[4];
        #pragma unroll
        for (int cm = 0; cm < 4; ++cm) {
            f32x4 acc = {0.f, 0.f, 0.f, 0.f};
            acc = MFMA32(v8[cm][0], pt80, acc);
            if (tn >= 2) acc = MFMA32(v8[cm][1], pt81, acc);
            c[cm] = pack4(acc, 1.0f);
        }
        o28[tn][0] = cat(c[0], c[1]);
        o28[tn][1] = cat(c[2], c[3]);
    }

    // resT = Wp @ out2T + bias; bounce through LDS; coalesced 1KB stores.
    bf16x8 wp0[4], wp1[4];
    float4 bias4[4];
    #pragma unroll
    for (int om = 0; om < 4; ++om) {
        wp0[om] = cat(*(const bf16x4*)(Wp + swz(om * 16 + r, g * 4)),
                      *(const bf16x4*)(Wp + swz(om * 16 + r, 16 + g * 4)));
        wp1[om] = cat(*(const bf16x4*)(Wp + swz(om * 16 + r, 32 + g * 4)),
                      *(const bf16x4*)(Wp + swz(om * 16 + r, 48 + g * 4)));
        bias4[om] = *(const float4*)(bp + om * 16 + g * 4);
    }
    #pragma unroll
    for (int tn = 0; tn < 4; ++tn) {
        // frag: row t = tn*16+r, cols om*16+g*4+j -> LDS[r][om*16+g*4]
        #pragma unroll
        for (int om = 0; om < 4; ++om) {
            f32x4 acc = {0.f, 0.f, 0.f, 0.f};
            acc = MFMA32(wp0[om], o28[tn][0], acc);
            acc = MFMA32(wp1[om], o28[tn][1], acc);
            float4 o;
            o.x = acc[0] + bias4[om].x; o.y = acc[1] + bias4[om].y;
            o.z = acc[2] + bias4[om].z; o.w = acc[3] + bias4[om].w;
            *(float4*)(bnc + r * BSTR + om * 16 + g * 4) = o;
        }
        asm volatile("s_waitcnt lgkmcnt(0)" ::: "memory");  // writes visible wave-wide
        // read back linearly, store 4 x 1KB contiguous (full 128B lines)
        #pragma unroll
        for (int i = 0; i < 4; ++i) {
            float4 v = *(const float4*)(bnc + (i * 4 + (lane >> 4)) * BSTR + (lane & 15) * 4);
            *(float4*)(ob + tn * 1024 + i * 256 + lane * 4) = v;
        }
        asm volatile("" ::: "memory");  // keep next tn's LDS writes after these reads
    }
}

__global__ __launch_bounds__(256, 2) void attn_fused_kernel(
    const float* __restrict__ x,              // [4096,64,64] fp32
    const float* __restrict__ wk,             // [64,64] fp32
    const float* __restrict__ wq,
    const float* __restrict__ wvw,
    const float* __restrict__ wp,
    const float* __restrict__ bp,             // [64] fp32
    float* __restrict__ out)                  // [4096,64,64] fp32
{
    __shared__ short lw[16384];               // 32 KB weights (bf16, swizzled)
    __shared__ float lbounce[4 * 16 * BSTR];  // 4 waves x 16-row bounce (17 KB)

    const int tid  = threadIdx.x;
    const int wv_  = tid >> 6;
    const int lane = tid & 63;
    const int r = lane & 15;
    const int g = lane >> 4;
    float* bnc = lbounce + wv_ * (16 * BSTR);
    const long b0 = (long)blockIdx.x * 4 + wv_;     // [0, 2048)
    const long b1 = b0 + 2048;

    // ---- issue batch-0 x loads ----
    const float* xb0 = x + b0 * 4096;
    float4 raw[8][2];
    #pragma unroll
    for (int f = 0; f < 8; ++f) {
        const float* p = xb0 + ((f >> 1) * 16 + r) * 64 + (f & 1) * 32 + g * 8;
        raw[f][0] = *(const float4*)p;
        raw[f][1] = *(const float4*)(p + 4);
    }

    // ---- FUSED weight staging: wave w converts fp32 matrix w -> swizzled LDS.
    // Wave-uniform source; lane stages one 64-elem row (256 B fp32 -> 128 B bf16).
    {
        const float* wsrc = (wv_ == 0) ? wk : (wv_ == 1) ? wq : (wv_ == 2) ? wvw : wp;
        const float s = (wv_ == 1) ? 0.125f : 1.0f;   // 2^-3: exact in bf16
        #pragma unroll
        for (int i = 0; i < 8; ++i) {
            const float* p = wsrc + lane * 64 + i * 8;
            float4 a = *(const float4*)p;
            float4 b = *(const float4*)(p + 4);
            *(bf16x8*)(lw + (wv_ * 64 + lane) * 64 + ((i ^ (lane & 7)) * 8))
                = cvt8s(a, b, s);
        }
    }

    // ---- convert batch-0 x to bf16 frags ----
    bf16x8 xf[8];
    #pragma unroll
    for (int f = 0; f < 8; ++f)
        xf[f] = cvt8(raw[f][0], raw[f][1]);

    __syncthreads();                          // weights visible (drains vmem too)

    // ---- PREFETCH batch-1 x: flies under batch-0's whole compute ----
    const float* xb1 = x + b1 * 4096;
    float4 raw1[8][2];
    #pragma unroll
    for (int f = 0; f < 8; ++f) {
        const float* p = xb1 + ((f >> 1) * 16 + r) * 64 + (f & 1) * 32 + g * 8;
        raw1[f][0] = *(const float4*)p;
        raw1[f][1] = *(const float4*)(p + 4);
    }

    // ---- batch 0: compute + store (stores drain under batch 1) ----
    compute_batch(lw, bnc, xf, bp, out + b0 * 4096, lane, r, g);

    // ---- batch 1: convert (waits prefetch), compute + store ----
    bf16x8 xf1[8];
    #pragma unroll
    for (int f = 0; f < 8; ++f)
        xf1[f] = cvt8(raw1[f][0], raw1[f][1]);

    compute_batch(lw, bnc, xf1, bp, out + b1 * 4096, lane, r, g);
}

extern "C" void kernel_launch(void* const* d_in, const int* in_sizes, int n_in,
                              void* d_out, int out_size, void* d_ws, size_t ws_size,
                              hipStream_t stream) {
    const float* x  = (const float*)d_in[0];
    const float* wk = (const float*)d_in[1];
    const float* wq = (const float*)d_in[2];
    const float* wv = (const float*)d_in[3];
    const float* wp = (const float*)d_in[4];
    const float* bp = (const float*)d_in[5];

    attn_fused_kernel<<<512, 256, 0, stream>>>(x, wk, wq, wv, wp, bp, (float*)d_out);
}